// Round 9
// baseline (645.612 us; speedup 1.0000x reference)
//
#include <hip/hip_runtime.h>

// 3-layer tanh-RNN (B=512, T=2048, D=6, H=32, fp32), MI355X.
// 3 waves/block (one per layer), pipelined with 1-phase skew, barrier every
// KS=8 steps. R5 measured 474us = DS-pipe-bound (46 DS ops/step/CU x ~11cy).
// R6/R7: dot products via DPP row_ror rotation (zero DS on the chain):
// lane L=[b5][b4][low4] holds h[16*b4+low]; 16x fmac(dpp ror:r) with
// pre-rotated weights computes each k-half dot. k-half combine =
// permlane16_swap; next-step relayout = permlane32_swap (both pure VALU,
// and robust to slot-order via sum/xor-extract identities).
// R6 failed (absmax 1.8): row_ror direction was assumed (n+R); actual
// convention is lane n reads (n-R). R7/R8 PROBES the direction at runtime
// (rotate lane-id, readfirstlane) and loads weights with the matching
// index, so either hardware convention validates.

#define T_LEN 2048
#define D_IN  6
#define KS    8
#define NPH   (T_LEN / KS)

typedef float f4 __attribute__((ext_vector_type(4)));
typedef unsigned int u2v __attribute__((ext_vector_type(2)));

#if defined(__has_builtin)
#  if __has_builtin(__builtin_amdgcn_permlane16_swap)
#    define HAVE_PL16 1
#  endif
#  if __has_builtin(__builtin_amdgcn_permlane32_swap)
#    define HAVE_PL32 1
#  endif
#endif

// tanh(v) = 1 - 2/(e^{2v}+1); exp + raw rcp, ~1e-7 rel, saturates correctly.
__device__ __forceinline__ float fast_tanh(float v) {
    float e = __expf(2.0f * v);
    float r = __builtin_amdgcn_rcpf(e + 1.0f);
    return __builtin_fmaf(-2.0f, r, 1.0f);
}

// sum over the two k-halves (lanes differing in bit4). Pure VALU.
// Robust: for any swap semantics where the two outputs hold {c[L], c[L^16]}
// (in either order), the sum is the combine.
__device__ __forceinline__ float xhalf16(float c) {
#ifdef HAVE_PL16
    u2v r = __builtin_amdgcn_permlane16_swap(__float_as_uint(c), __float_as_uint(c),
                                             false, false);
    return __uint_as_float(r.x) + __uint_as_float(r.y);
#else
    return c + __shfl_xor(c, 16, 64);
#endif
}

// value held by lane L^32. xor-extract: r.x^r.y^v = partner regardless of
// which output slot holds own vs swapped.
__device__ __forceinline__ float other32(float v) {
#ifdef HAVE_PL32
    u2v r = __builtin_amdgcn_permlane32_swap(__float_as_uint(v), __float_as_uint(v),
                                             false, false);
    return __uint_as_float(r.x ^ r.y ^ __float_as_uint(v));
#else
    return __shfl_xor(v, 32, 64);
#endif
}

// DPP row_ror:R within 16-lane rows (bits 4,5 preserved). Direction probed
// at runtime; weights are loaded to match.
template<int R>
__device__ __forceinline__ float rot16(float v) {
    if constexpr (R == 0) return v;
    else return __int_as_float(__builtin_amdgcn_update_dpp(
        0, __float_as_int(v), 0x120 | R, 0xF, 0xF, true));
}
template<int R>
__device__ __forceinline__ int rot16i(int v) {
    if constexpr (R == 0) return v;
    else return __builtin_amdgcn_update_dpp(0, v, 0x120 | R, 0xF, 0xF, true);
}

#define SELF4(r0, r1, r2, r3)                                   \
    a0 = __builtin_fmaf(rot16<r0>(hs), ws[r0], a0);             \
    a1 = __builtin_fmaf(rot16<r1>(hs), ws[r1], a1);             \
    a2 = __builtin_fmaf(rot16<r2>(hs), ws[r2], a2);             \
    a3 = __builtin_fmaf(rot16<r3>(hs), ws[r3], a3);

#define CROSS4(r0, r1, r2, r3)                                  \
    a0 = __builtin_fmaf(rot16<r0>(hxv), wx[r0], a0);            \
    a1 = __builtin_fmaf(rot16<r1>(hxv), wx[r1], a1);            \
    a2 = __builtin_fmaf(rot16<r2>(hxv), wx[r2], a2);            \
    a3 = __builtin_fmaf(rot16<r3>(hxv), wx[r3], a3);

__global__ void __launch_bounds__(192) rnn3_dpp2(
    const float* __restrict__ x,     // [B, T, 6]
    const float* __restrict__ Wih0,  // [32, 6]
    const float* __restrict__ WihR,  // [2, 32, 32]
    const float* __restrict__ Whh,   // [3, 32, 32]
    const float* __restrict__ bih,   // [3, 32]
    const float* __restrict__ bhh,   // [3, 32]
    const float* __restrict__ fcw,   // [6, 32]
    const float* __restrict__ fcb,   // [6]
    float* __restrict__ out)         // [B, 6]
{
    const int b   = blockIdx.x;
    const int tid = threadIdx.x;
    const int wid = tid >> 6;        // 0,1,2 -> layer
    const int L   = tid & 63;
    const int low = L & 15;
    const int b4  = (L >> 4) & 1;    // k-half p
    const int b5  = L >> 5;
    const int j   = 16 * b5 + low;   // this lane's output index
    const int j0  = L & 31;          // = 16*b4 + low (k-init / ring index)

    __shared__ float ring[2][2][KS][32];            // [layer][buf][s][j]
    __shared__ float h3buf[32];
    __shared__ __align__(16) float xstage[KS * D_IN];
    __shared__ float xap[2][KS][32];                // x-projection (+layer0 bias)

    // ---- DIRECTION PROBE: does row_ror:1 deliver lane (n-1)&15 or (n+1)&15?
    // lane0 (low=0) receives low of the source lane: 15 -> reads n-1 (dir=-1),
    // 1 -> reads n+1 (dir=+1). readfirstlane = lane 0 of each wave.
    const int probe = __builtin_amdgcn_readfirstlane(rot16i<1>(low));
    const int dir   = (probe == 15) ? -1 : 1;

    // ---- rotated weights matched to the probed direction:
    // at fmac step r the lane sees h[16*b4 + ((low + dir*r)&15)].
    float ws[16];
    {
        const float* row = Whh + wid * 1024 + j * 32;
#pragma unroll
        for (int r = 0; r < 16; ++r) ws[r] = row[16 * b4 + ((low + dir * r) & 15)];
    }
    float wx[16];
    if (wid > 0) {
        const float* row = WihR + (wid - 1) * 1024 + j * 32;
#pragma unroll
        for (int r = 0; r < 16; ++r) wx[r] = row[16 * b4 + ((low + dir * r) & 15)];
    }
    const float bsj = bih[wid * 32 + j] + bhh[wid * 32 + j];

    // ---- wave0 x-projection constants (j0-indexed mapping) ----
    const int sblk = b5;             // which 4-step group this lane computes
    float w0c[D_IN];
    float bs0 = 0.0f;
    if (wid == 0) {
#pragma unroll
        for (int d = 0; d < D_IN; ++d) w0c[d] = Wih0[j0 * D_IN + d];
        bs0 = bih[j0] + bhh[j0];
    }

    const float* xg = x + (size_t)b * (T_LEN * D_IN);
    float xld = 0.0f;

    // ---- wave0 prologue: build xap[0], prefetch phase-1 x ----
    if (wid == 0) {
        if (L < KS * D_IN) xstage[L] = xg[L];
        float Xf[24];
        {
            const f4* xs = (const f4*)&xstage[24 * sblk];
            f4 v0 = xs[0], v1 = xs[1], v2 = xs[2], v3 = xs[3], v4 = xs[4], v5 = xs[5];
#pragma unroll
            for (int i = 0; i < 4; ++i) {
                Xf[i] = v0[i]; Xf[4 + i] = v1[i]; Xf[8 + i] = v2[i];
                Xf[12 + i] = v3[i]; Xf[16 + i] = v4[i]; Xf[20 + i] = v5[i];
            }
        }
#pragma unroll
        for (int i = 0; i < 4; ++i) {
            float acc = bs0;
#pragma unroll
            for (int d = 0; d < D_IN; ++d)
                acc = __builtin_fmaf(Xf[6 * i + d], w0c[d], acc);
            xap[0][4 * sblk + i][j0] = acc;
        }
        if (NPH > 1 && L < KS * D_IN) xld = xg[KS * D_IN + L];
    }

    float hs = 0.0f;                       // h_wid(t-1)[16*b4+low]
    const bool needswap = (b4 != b5);

#pragma unroll 1
    for (int ph = 0; ph < NPH + 2; ++ph) {
        const int q = ph - wid;
        if (q >= 0 && q < NPH) {
            const int qb = q & 1;
            if (wid == 0) {
                float xabuf[KS];
#pragma unroll
                for (int s = 0; s < KS; ++s) xabuf[s] = xap[qb][s][j];
#pragma unroll
                for (int s = 0; s < KS; ++s) {
                    float a0 = 0.f, a1 = 0.f, a2 = 0.f, a3 = 0.f;
                    SELF4(0, 1, 2, 3) SELF4(4, 5, 6, 7)
                    SELF4(8, 9, 10, 11) SELF4(12, 13, 14, 15)
                    float full = xhalf16((a0 + a1) + (a2 + a3));
                    float h = fast_tanh(full + xabuf[s]);
                    if (!b4) ring[0][qb][s][j] = h;
                    float o = other32(h);
                    hs = needswap ? o : h;
                }
                // build xap for phase q+1 (off the recurrent chain)
                if (q + 1 < NPH) {
                    if (L < KS * D_IN) xstage[L] = xld;
                    float Xf[24];
                    {
                        const f4* xs = (const f4*)&xstage[24 * sblk];
                        f4 v0 = xs[0], v1 = xs[1], v2 = xs[2], v3 = xs[3], v4 = xs[4], v5 = xs[5];
#pragma unroll
                        for (int i = 0; i < 4; ++i) {
                            Xf[i] = v0[i]; Xf[4 + i] = v1[i]; Xf[8 + i] = v2[i];
                            Xf[12 + i] = v3[i]; Xf[16 + i] = v4[i]; Xf[20 + i] = v5[i];
                        }
                    }
#pragma unroll
                    for (int i = 0; i < 4; ++i) {
                        float acc = bs0;
#pragma unroll
                        for (int d = 0; d < D_IN; ++d)
                            acc = __builtin_fmaf(Xf[6 * i + d], w0c[d], acc);
                        xap[qb ^ 1][4 * sblk + i][j0] = acc;
                    }
                    if (q + 2 < NPH && L < KS * D_IN)
                        xld = xg[(q + 2) * (KS * D_IN) + L];
                }
            } else {
                float hxbuf[KS];
#pragma unroll
                for (int s = 0; s < KS; ++s) hxbuf[s] = ring[wid - 1][qb][s][j0];
#pragma unroll
                for (int s = 0; s < KS; ++s) {
                    const float hxv = hxbuf[s];
                    float a0 = 0.f, a1 = 0.f, a2 = 0.f, a3 = 0.f;
                    SELF4(0, 1, 2, 3)   CROSS4(0, 1, 2, 3)
                    SELF4(4, 5, 6, 7)   CROSS4(4, 5, 6, 7)
                    SELF4(8, 9, 10, 11) CROSS4(8, 9, 10, 11)
                    SELF4(12, 13, 14, 15) CROSS4(12, 13, 14, 15)
                    float full = xhalf16((a0 + a1) + (a2 + a3));
                    float h = fast_tanh(full + bsj);
                    if (wid == 1 && !b4) ring[1][qb][s][j] = h;
                    float o = other32(h);
                    hs = needswap ? o : h;
                }
            }
        }
        __syncthreads();
    }

    // ---- head (wave2, in-wave order): hs = h3(T-1)[L&31] in every lane ----
    if (wid == 2) {
        if (L < 32) h3buf[L] = hs;
        if (L < D_IN) {
            float acc = fcb[L];
            const f4* fw = (const f4*)(fcw + L * 32);
            const f4* hv = (const f4*)h3buf;
#pragma unroll
            for (int m = 0; m < 8; ++m) {
                f4 w4 = fw[m], h4 = hv[m];
#pragma unroll
                for (int i = 0; i < 4; ++i) acc = __builtin_fmaf(h4[i], w4[i], acc);
            }
            out[b * D_IN + L] = acc;
        }
    }
}

extern "C" void kernel_launch(void* const* d_in, const int* in_sizes, int n_in,
                              void* d_out, int out_size, void* d_ws, size_t ws_size,
                              hipStream_t stream) {
    const float* x    = (const float*)d_in[0];
    const float* Wih0 = (const float*)d_in[1];
    const float* WihR = (const float*)d_in[2];
    const float* Whh  = (const float*)d_in[3];
    const float* bih  = (const float*)d_in[4];
    const float* bhh  = (const float*)d_in[5];
    const float* fcw  = (const float*)d_in[6];
    const float* fcb  = (const float*)d_in[7];
    float* outp = (float*)d_out;

    const int B = in_sizes[0] / (T_LEN * D_IN);  // 512
    rnn3_dpp2<<<B, 192, 0, stream>>>(x, Wih0, WihR, Whh, bih, bhh, fcw, fcb, outp);
}